// Round 1
// baseline (211.934 us; speedup 1.0000x reference)
//
#include <hip/hip_runtime.h>

typedef short short8 __attribute__((ext_vector_type(8)));
typedef float f32x4 __attribute__((ext_vector_type(4)));

#define GLOAD_LDS(src, dst) \
  __builtin_amdgcn_global_load_lds((const __attribute__((address_space(1))) void*)(src), \
                                   (__attribute__((address_space(3))) void*)(dst), 16, 0, 0)

__device__ __forceinline__ unsigned short f2b(float f){
  union { float f; unsigned u; } v; v.f = f;
  unsigned u = v.u;
  u = (u + 0x7fffu + ((u >> 16) & 1u)) >> 16;   // RNE f32->bf16
  return (unsigned short)u;
}

// ---------------- f32 -> bf16 conversion (vectorized) ----------------
__global__ __launch_bounds__(256) void convf2b(const float* __restrict__ in,
                                               unsigned short* __restrict__ out, int n4){
  int i = blockIdx.x * 256 + threadIdx.x;
  if (i < n4){
    const float4 v = reinterpret_cast<const float4*>(in)[i];
    ushort4 o;
    o.x = f2b(v.x); o.y = f2b(v.y); o.z = f2b(v.z); o.w = f2b(v.w);
    reinterpret_cast<ushort4*>(out)[i] = o;
  }
}

// ---------------- src_mask dtype detection ----------------
// If the bool mask is stored as u8, reading it as int32 gives values >1 w.h.p.
__global__ void detect_mask_dtype(const int* __restrict__ src, int* __restrict__ flag){
  if (threadIdx.x == 0 && blockIdx.x == 0){
    int f = 0;
    for (int i = 0; i < 1024; i++){
      unsigned v = ((const unsigned*)src)[i];
      if (v > 1u) f = 1;
    }
    *flag = f;  // 1 => u8 bools, 0 => int32
  }
}

// ---------------- pack combined mask into bits ----------------
__global__ __launch_bounds__(256) void maskpack(const int* __restrict__ tgt,
                                                const void* __restrict__ src,
                                                const int* __restrict__ flag,
                                                unsigned long long* __restrict__ mp){
  size_t gt = (size_t)blockIdx.x * 256 + threadIdx.x;   // (b*2048+i)*2048 + j
  int j = (int)(gt & 2047);
  size_t bi = gt >> 11;
  int b = (int)(bi >> 11);
  bool s;
  if (*flag) s = ((const unsigned char*)src)[b * 2048 + j] != 0;
  else       s = ((const int*)src)[b * 2048 + j] != 0;
  bool bit = (tgt[gt] != 0) && s;
  unsigned long long m = __ballot(bit ? 1 : 0);
  if ((threadIdx.x & 63) == 0) mp[gt >> 6] = m;
}

// ---------------- m97-style BT GEMM: C[m,e] = sum_k A[m,k]*B[e,k] ----------------
// MODE 0: out bf16 -> q_ws [b,h,n,d]
// MODE 1: e<1024 -> k_ws [b,h,n,d]; e>=1024 -> v^T ws [b,h,d,n] (packed 8B stores)
// MODE 2: out f32 -> d_out[m*1024+e] + bias[e]
template<int MODE>
__global__ __launch_bounds__(256) void gemm_bt(const unsigned short* __restrict__ A,
                                               const unsigned short* __restrict__ Bw,
                                               unsigned short* __restrict__ o0,
                                               unsigned short* __restrict__ o1,
                                               float* __restrict__ fout,
                                               const float* __restrict__ bias){
  constexpr int K = 1024;
  const int tid = threadIdx.x;
  const int lane = tid & 63, wid = tid >> 6;
  const int l15 = lane & 15, l4 = lane >> 4;
  const int m0 = blockIdx.y * 128, n0 = blockIdx.x * 128;
  const int wm = wid >> 1, wn = wid & 1;
  __shared__ unsigned short lA[128 * 32];
  __shared__ unsigned short lB[128 * 32];
  f32x4 acc[4][4] = {};

  for (int k0 = 0; k0 < K; k0 += 32){
    #pragma unroll
    for (int s = 0; s < 2; s++){
      const int c = tid + s * 256;          // 512 chunks of 16B per tile
      const int row = c >> 2, q = c & 3;
      const unsigned short* sa = A  + (size_t)(m0 + row) * K + k0 + q * 8;
      const unsigned short* sb = Bw + (size_t)(n0 + row) * K + k0 + q * 8;
      unsigned short* da = lA + (wid * 64 + s * 256) * 8;   // wave-uniform base
      unsigned short* db = lB + (wid * 64 + s * 256) * 8;
      GLOAD_LDS(sa, da);
      GLOAD_LDS(sb, db);
    }
    __syncthreads();
    short8 af[4], bf[4];
    #pragma unroll
    for (int m = 0; m < 4; m++)
      af[m] = *reinterpret_cast<const short8*>(&lA[(wm * 64 + m * 16 + l15) * 32 + l4 * 8]);
    #pragma unroll
    for (int n = 0; n < 4; n++)
      bf[n] = *reinterpret_cast<const short8*>(&lB[(wn * 64 + n * 16 + l15) * 32 + l4 * 8]);
    #pragma unroll
    for (int m = 0; m < 4; m++)
      #pragma unroll
      for (int n = 0; n < 4; n++)
        acc[m][n] = __builtin_amdgcn_mfma_f32_16x16x32_bf16(af[m], bf[n], acc[m][n], 0, 0, 0);
    __syncthreads();
  }

  const int eb = n0 + wn * 64;
  const int mb = m0 + wm * 64 + l4 * 4;
  #pragma unroll
  for (int n = 0; n < 4; n++){
    const int e = eb + n * 16 + l15;
    #pragma unroll
    for (int m = 0; m < 4; m++){
      const int mm = mb + m * 16;
      if constexpr (MODE == 2){
        const float bv = bias[e];
        #pragma unroll
        for (int r = 0; r < 4; r++)
          fout[(size_t)(mm + r) * 1024 + e] = acc[m][n][r] + bv;
      } else if constexpr (MODE == 0){
        const int h = e >> 6, d = e & 63;
        #pragma unroll
        for (int r = 0; r < 4; r++){
          const int row = mm + r, b = row >> 11, nn = row & 2047;
          o0[(((size_t)b * 16 + h) * 2048 + nn) * 64 + d] = f2b(acc[m][n][r]);
        }
      } else {  // MODE 1
        if (e < 1024){
          const int h = e >> 6, d = e & 63;
          #pragma unroll
          for (int r = 0; r < 4; r++){
            const int row = mm + r, b = row >> 11, nn = row & 2047;
            o0[(((size_t)b * 16 + h) * 2048 + nn) * 64 + d] = f2b(acc[m][n][r]);
          }
        } else {
          const int ee = e - 1024, h = ee >> 6, d = ee & 63;
          const int b = mm >> 11, nn = mm & 2047;   // 4 consecutive n, same b
          ushort4 pk;
          pk.x = f2b(acc[m][n][0]); pk.y = f2b(acc[m][n][1]);
          pk.z = f2b(acc[m][n][2]); pk.w = f2b(acc[m][n][3]);
          *reinterpret_cast<ushort4*>(&o1[(((size_t)b * 16 + h) * 64 + d) * 2048 + nn]) = pk;
        }
      }
    }
  }
}

// ---------------- flash attention ----------------
// grid: (32 q-tiles, 32 bh). 4 waves x 16 q-rows. KV tiles of 64.
// S^T = mfma(K, Q): lane holds S[j = l4*4+reg (+16*jt)][i = l15] -> softmax reduce
// over j via in-lane + shfl_xor(16/32). P -> per-wave LDS (stride 72, 16B-aligned)
// -> PV A-operand; V^T tile (XOR-swizzled) -> PV B-operand.
__global__ __launch_bounds__(256) void attn(const unsigned short* __restrict__ qw,
                                            const unsigned short* __restrict__ kw,
                                            const unsigned short* __restrict__ vtw,
                                            const unsigned long long* __restrict__ mp,
                                            unsigned short* __restrict__ ao){
  const int bh = blockIdx.y, b = bh >> 4, h = bh & 15;
  const int qbase = blockIdx.x * 64;
  const int tid = threadIdx.x, wid = tid >> 6, lane = tid & 63;
  const int l15 = lane & 15, l4 = lane >> 4;
  __shared__ unsigned short lK[64 * 64];     // [j][d], bytes XOR ((j&7)<<4)
  __shared__ unsigned short lV[64 * 64];     // [d][j] (V^T), bytes XOR ((d&7)<<4)
  __shared__ unsigned short lP[4][16 * 72];  // per-wave P, row-stride 72 bf16

  const int qrow = qbase + wid * 16 + l15;
  const unsigned short* qp = qw + ((size_t)bh * 2048 + qrow) * 64 + l4 * 8;
  const short8 qf0 = *reinterpret_cast<const short8*>(qp);
  const short8 qf1 = *reinterpret_cast<const short8*>(qp + 32);

  float m_i = -1e30f, l_i = 0.f;
  f32x4 o[4] = {};
  const int sw = (l15 & 7) << 4;

  for (int j0 = 0; j0 < 2048; j0 += 64){
    #pragma unroll
    for (int s = 0; s < 2; s++){
      const int c = tid + s * 256;
      const int r = c >> 3, cc = (c & 7) ^ (r & 7);   // pre-swizzled global source
      const unsigned short* sk = kw  + ((size_t)bh * 2048 + j0 + r) * 64 + cc * 8;
      const unsigned short* sv = vtw + ((size_t)bh * 64 + r) * 2048 + j0 + cc * 8;
      unsigned short* dk = lK + (wid * 64 + s * 256) * 8;
      unsigned short* dv = lV + (wid * 64 + s * 256) * 8;
      GLOAD_LDS(sk, dk);
      GLOAD_LDS(sv, dv);
    }
    __syncthreads();

    // S^T tiles
    f32x4 st[4];
    #pragma unroll
    for (int jt = 0; jt < 4; jt++){
      const int base = (jt * 16 + l15) * 128 + l4 * 16;   // bytes
      const short8 a0 = *reinterpret_cast<const short8*>((char*)lK + ((base     ) ^ sw));
      const short8 a1 = *reinterpret_cast<const short8*>((char*)lK + ((base + 64) ^ sw));
      f32x4 z = {0.f, 0.f, 0.f, 0.f};
      z = __builtin_amdgcn_mfma_f32_16x16x32_bf16(a0, qf0, z, 0, 0, 0);
      z = __builtin_amdgcn_mfma_f32_16x16x32_bf16(a1, qf1, z, 0, 0, 0);
      st[jt] = z;
    }

    const unsigned long long mk = mp[((size_t)b * 2048 + qrow) * 32 + (j0 >> 6)];
    float tmax = -1e30f;
    #pragma unroll
    for (int jt = 0; jt < 4; jt++)
      #pragma unroll
      for (int r = 0; r < 4; r++){
        const int jl = jt * 16 + l4 * 4 + r;
        float s = st[jt][r] * 0.125f;
        if (!((mk >> jl) & 1ull)) s = -1e30f;
        st[jt][r] = s;
        tmax = fmaxf(tmax, s);
      }
    tmax = fmaxf(tmax, __shfl_xor(tmax, 16));
    tmax = fmaxf(tmax, __shfl_xor(tmax, 32));
    const float mnew = fmaxf(m_i, tmax);
    const float fac = __expf(m_i - mnew);
    float psum = 0.f;
    #pragma unroll
    for (int jt = 0; jt < 4; jt++){
      ushort4 pk;
      #pragma unroll
      for (int r = 0; r < 4; r++){
        const int jl = jt * 16 + l4 * 4 + r;
        float p = __expf(st[jt][r] - mnew);
        p = ((mk >> jl) & 1ull) ? p : 0.f;   // bit-mult: fully-masked tile stays 0
        psum += p;
        ((unsigned short*)&pk)[r] = f2b(p);
      }
      *reinterpret_cast<ushort4*>(&lP[wid][(size_t)l15 * 72 + jt * 16 + l4 * 4]) = pk;
    }
    psum += __shfl_xor(psum, 16);
    psum += __shfl_xor(psum, 32);
    l_i = l_i * fac + psum;
    m_i = mnew;

    // rescale O (per-row factors live in lanes 0..15)
    #pragma unroll
    for (int r = 0; r < 4; r++){
      const float fr = __shfl(fac, l4 * 4 + r);
      #pragma unroll
      for (int dt = 0; dt < 4; dt++) o[dt][r] *= fr;
    }

    // PV
    #pragma unroll
    for (int ks = 0; ks < 2; ks++){
      const short8 pa = *reinterpret_cast<const short8*>(&lP[wid][(size_t)l15 * 72 + ks * 32 + l4 * 8]);
      #pragma unroll
      for (int dt = 0; dt < 4; dt++){
        const int base = (dt * 16 + l15) * 128 + ks * 64 + l4 * 16;
        const short8 bv = *reinterpret_cast<const short8*>((char*)lV + (base ^ sw));
        o[dt] = __builtin_amdgcn_mfma_f32_16x16x32_bf16(pa, bv, o[dt], 0, 0, 0);
      }
    }
    __syncthreads();
  }

  #pragma unroll
  for (int r = 0; r < 4; r++){
    const float li = __shfl(l_i, l4 * 4 + r);
    const float inv = 1.0f / li;
    const int n = qbase + wid * 16 + l4 * 4 + r;
    #pragma unroll
    for (int dt = 0; dt < 4; dt++){
      const int e = h * 64 + dt * 16 + l15;
      ao[((size_t)b * 2048 + n) * 1024 + e] = f2b(o[dt][r] * inv);
    }
  }
}

extern "C" void kernel_launch(void* const* d_in, const int* in_sizes, int n_in,
                              void* d_out, int out_size, void* d_ws, size_t ws_size,
                              hipStream_t stream){
  const float* x   = (const float*)d_in[0];
  const float* ctx = (const float*)d_in[1];
  const int*   tgt = (const int*)d_in[2];
  const void*  src = d_in[3];
  const float* Wq  = (const float*)d_in[4];
  const float* Wk  = (const float*)d_in[5];
  const float* Wv  = (const float*)d_in[6];
  const float* Wo  = (const float*)d_in[7];
  const float* bo  = (const float*)d_in[8];
  float* out = (float*)d_out;

  char* w = (char*)d_ws;
  unsigned short* xb   = (unsigned short*)(w);
  unsigned short* cb   = (unsigned short*)(w + (8u << 20));
  unsigned short* wqb  = (unsigned short*)(w + (16u << 20));
  unsigned short* wkvb = (unsigned short*)(w + (18u << 20));
  unsigned short* wob  = (unsigned short*)(w + (22u << 20));
  unsigned short* qws  = (unsigned short*)(w + (24u << 20));
  unsigned short* kws  = (unsigned short*)(w + (32u << 20));
  unsigned short* vtw  = (unsigned short*)(w + (40u << 20));
  unsigned short* ao   = (unsigned short*)(w + (48u << 20));
  unsigned long long* mp = (unsigned long long*)(w + (56u << 20));
  int* flag = (int*)(w + (57u << 20));

  convf2b<<<4096, 256, 0, stream>>>(x,   xb, 1048576);
  convf2b<<<4096, 256, 0, stream>>>(ctx, cb, 1048576);
  convf2b<<<1024, 256, 0, stream>>>(Wq, wqb, 262144);
  convf2b<<<1024, 256, 0, stream>>>(Wk, wkvb, 262144);
  convf2b<<<1024, 256, 0, stream>>>(Wv, wkvb + (1u << 20), 262144);
  convf2b<<<1024, 256, 0, stream>>>(Wo, wob, 262144);
  detect_mask_dtype<<<1, 64, 0, stream>>>((const int*)src, flag);
  maskpack<<<32768, 256, 0, stream>>>(tgt, src, flag, mp);

  gemm_bt<0><<<dim3(8, 32),  256, 0, stream>>>(xb, wqb,  qws, nullptr, nullptr, nullptr);
  gemm_bt<1><<<dim3(16, 32), 256, 0, stream>>>(cb, wkvb, kws, vtw,     nullptr, nullptr);
  attn<<<dim3(32, 32), 256, 0, stream>>>(qws, kws, vtw, mp, ao);
  gemm_bt<2><<<dim3(8, 32),  256, 0, stream>>>(ao, wob,  nullptr, nullptr, out, bo);
}

// Round 2
// 201.610 us; speedup vs baseline: 1.0512x; 1.0512x over previous
//
#include <hip/hip_runtime.h>

typedef short short8 __attribute__((ext_vector_type(8)));
typedef float f32x4 __attribute__((ext_vector_type(4)));

#define GLOAD_LDS(src, dst) \
  __builtin_amdgcn_global_load_lds((const __attribute__((address_space(1))) void*)(src), \
                                   (__attribute__((address_space(3))) void*)(dst), 16, 0, 0)

__device__ __forceinline__ unsigned short f2b(float f){
  __bf16 h = (__bf16)f;                       // RNE, v_cvt_pk_bf16_f32 via compiler
  return __builtin_bit_cast(unsigned short, h);
}

// ---------------- fused f32 -> bf16 conversion for all 6 inputs ----------------
// vec4 segments: x 1048576 | ctx 1048576 | wq 262144 | wk 262144 | wv 262144 | wo 262144
__global__ __launch_bounds__(256) void convall(const float* __restrict__ x, const float* __restrict__ ctx,
    const float* __restrict__ wq, const float* __restrict__ wk, const float* __restrict__ wv,
    const float* __restrict__ wo,
    unsigned short* __restrict__ xb, unsigned short* __restrict__ cb, unsigned short* __restrict__ wqb,
    unsigned short* __restrict__ wkvb, unsigned short* __restrict__ wob){
  const int i = blockIdx.x * 256 + threadIdx.x;
  const float* src; unsigned short* dst; int so, doff;
  if (i < 1048576)      { src = x;   dst = xb;   so = i;           doff = so; }
  else if (i < 2097152) { src = ctx; dst = cb;   so = i - 1048576; doff = so; }
  else if (i < 2359296) { src = wq;  dst = wqb;  so = i - 2097152; doff = so; }
  else if (i < 2621440) { src = wk;  dst = wkvb; so = i - 2359296; doff = so; }
  else if (i < 2883584) { src = wv;  dst = wkvb; so = i - 2621440; doff = so + 262144; }
  else                  { src = wo;  dst = wob;  so = i - 2883584; doff = so; }
  const float4 v = reinterpret_cast<const float4*>(src)[so];
  ushort4 o;
  o.x = f2b(v.x); o.y = f2b(v.y); o.z = f2b(v.z); o.w = f2b(v.w);
  reinterpret_cast<ushort4*>(dst)[doff] = o;
}

// ---------------- src_mask dtype detection ----------------
__global__ void detect_mask_dtype(const int* __restrict__ src, int* __restrict__ flag){
  if (threadIdx.x == 0 && blockIdx.x == 0){
    int f = 0;
    for (int i = 0; i < 1024; i++){
      unsigned v = ((const unsigned*)src)[i];
      if (v > 1u) f = 1;
    }
    *flag = f;  // 1 => u8 bools, 0 => int32
  }
}

// ---------------- pack combined mask into bits ----------------
__global__ __launch_bounds__(256) void maskpack(const int* __restrict__ tgt,
                                                const void* __restrict__ src,
                                                const int* __restrict__ flag,
                                                unsigned long long* __restrict__ mp){
  size_t gt = (size_t)blockIdx.x * 256 + threadIdx.x;   // (b*2048+i)*2048 + j
  int j = (int)(gt & 2047);
  size_t bi = gt >> 11;
  int b = (int)(bi >> 11);
  bool s;
  if (*flag) s = ((const unsigned char*)src)[b * 2048 + j] != 0;
  else       s = ((const int*)src)[b * 2048 + j] != 0;
  bool bit = (tgt[gt] != 0) && s;
  unsigned long long m = __ballot(bit ? 1 : 0);
  if ((threadIdx.x & 63) == 0) mp[gt >> 6] = m;
}

// ---------------- double-buffered BT GEMM: C[m,e] = sum_k A[m,k]*B[e,k] ----------------
// MODE 0: out bf16*QSCALE -> q_ws [b,h,n,d]   (QSCALE = 0.125*log2e for exp2-domain softmax)
// MODE 1: e<1024 -> k_ws [b,h,n,d]; e>=1024 -> v^T ws [b,h,d,n]
// MODE 2: out f32 -> d_out[m*1024+e] + bias[e]
template<int MODE>
__global__ __launch_bounds__(256) void gemm_bt(const unsigned short* __restrict__ A,
                                               const unsigned short* __restrict__ Bw,
                                               unsigned short* __restrict__ o0,
                                               unsigned short* __restrict__ o1,
                                               float* __restrict__ fout,
                                               const float* __restrict__ bias){
  constexpr int K = 1024;
  const int tid = threadIdx.x;
  const int lane = tid & 63, wid = tid >> 6;
  const int l15 = lane & 15, l4 = lane >> 4;
  const int m0 = blockIdx.y * 128, n0 = blockIdx.x * 128;
  const int wm = wid >> 1, wn = wid & 1;
  __shared__ unsigned short lA[2][128 * 32];
  __shared__ unsigned short lB[2][128 * 32];
  f32x4 acc[4][4] = {};

  const int r0 = tid >> 2, q0 = tid & 3;
  const int r1 = (tid + 256) >> 2;
  const unsigned short* a0p = A  + (size_t)(m0 + r0) * K + q0 * 8;
  const unsigned short* a1p = A  + (size_t)(m0 + r1) * K + q0 * 8;
  const unsigned short* b0p = Bw + (size_t)(n0 + r0) * K + q0 * 8;
  const unsigned short* b1p = Bw + (size_t)(n0 + r1) * K + q0 * 8;
  const int d0 = (wid * 64) * 8, d1 = (wid * 64 + 256) * 8;

#define G_STAGE(K0, BUF) { \
    GLOAD_LDS(a0p + (K0), &lA[BUF][d0]); \
    GLOAD_LDS(a1p + (K0), &lA[BUF][d1]); \
    GLOAD_LDS(b0p + (K0), &lB[BUF][d0]); \
    GLOAD_LDS(b1p + (K0), &lB[BUF][d1]); }

  G_STAGE(0, 0)
  __syncthreads();
  int cur = 0;
  for (int k0 = 0; k0 < K; k0 += 32){
    if (k0 < K - 32) G_STAGE(k0 + 32, cur ^ 1)
    short8 af[4], bf[4];
    #pragma unroll
    for (int m = 0; m < 4; m++)
      af[m] = *reinterpret_cast<const short8*>(&lA[cur][(wm * 64 + m * 16 + l15) * 32 + l4 * 8]);
    #pragma unroll
    for (int n = 0; n < 4; n++)
      bf[n] = *reinterpret_cast<const short8*>(&lB[cur][(wn * 64 + n * 16 + l15) * 32 + l4 * 8]);
    #pragma unroll
    for (int m = 0; m < 4; m++)
      #pragma unroll
      for (int n = 0; n < 4; n++)
        acc[m][n] = __builtin_amdgcn_mfma_f32_16x16x32_bf16(af[m], bf[n], acc[m][n], 0, 0, 0);
    __syncthreads();
    cur ^= 1;
  }
#undef G_STAGE

  const int eb = n0 + wn * 64;
  const int mb = m0 + wm * 64 + l4 * 4;
  #pragma unroll
  for (int n = 0; n < 4; n++){
    const int e = eb + n * 16 + l15;
    #pragma unroll
    for (int m = 0; m < 4; m++){
      const int mm = mb + m * 16;
      if constexpr (MODE == 2){
        const float bv = bias[e];
        #pragma unroll
        for (int r = 0; r < 4; r++)
          fout[(size_t)(mm + r) * 1024 + e] = acc[m][n][r] + bv;
      } else if constexpr (MODE == 0){
        const int h = e >> 6, d = e & 63;
        #pragma unroll
        for (int r = 0; r < 4; r++){
          const int row = mm + r, b = row >> 11, nn = row & 2047;
          o0[(((size_t)b * 16 + h) * 2048 + nn) * 64 + d] = f2b(acc[m][n][r] * 0.18033688011112042f);
        }
      } else {  // MODE 1
        if (e < 1024){
          const int h = e >> 6, d = e & 63;
          #pragma unroll
          for (int r = 0; r < 4; r++){
            const int row = mm + r, b = row >> 11, nn = row & 2047;
            o0[(((size_t)b * 16 + h) * 2048 + nn) * 64 + d] = f2b(acc[m][n][r]);
          }
        } else {
          const int ee = e - 1024, h = ee >> 6, d = ee & 63;
          const int b = mm >> 11, nn = mm & 2047;
          ushort4 pk;
          pk.x = f2b(acc[m][n][0]); pk.y = f2b(acc[m][n][1]);
          pk.z = f2b(acc[m][n][2]); pk.w = f2b(acc[m][n][3]);
          *reinterpret_cast<ushort4*>(&o1[(((size_t)b * 16 + h) * 64 + d) * 2048 + nn]) = pk;
        }
      }
    }
  }
}

// ---------------- flash attention, 2-phase pipelined ----------------
__global__ __launch_bounds__(256) void attn(const unsigned short* __restrict__ qw,
                                            const unsigned short* __restrict__ kw,
                                            const unsigned short* __restrict__ vtw,
                                            const unsigned long long* __restrict__ mp,
                                            unsigned short* __restrict__ ao){
  const int bh = blockIdx.y, b = bh >> 4, h = bh & 15;
  const int qbase = blockIdx.x * 64;
  const int tid = threadIdx.x, wid = tid >> 6, lane = tid & 63;
  const int l15 = lane & 15, l4 = lane >> 4;
  __shared__ unsigned short lK[2][64 * 64];   // [j][d], bytes XOR ((j&7)<<4)
  __shared__ unsigned short lV[2][64 * 64];   // [d][j] (V^T), bytes XOR ((d&7)<<4)
  __shared__ unsigned short lP[4][16 * 64];   // per-wave P, bytes XOR ((i&7)<<4)

  const int qrow = qbase + wid * 16 + l15;
  const unsigned short* qp = qw + ((size_t)bh * 2048 + qrow) * 64 + l4 * 8;
  const short8 qf0 = *reinterpret_cast<const short8*>(qp);
  const short8 qf1 = *reinterpret_cast<const short8*>(qp + 32);

  // staging addresses (loop-invariant parts)
  const int c0 = tid,        r0 = c0 >> 3, cc0 = (c0 & 7) ^ (r0 & 7);
  const int c1 = tid + 256,  r1 = c1 >> 3, cc1 = (c1 & 7) ^ (r1 & 7);
  const unsigned short* kb = kw  + (size_t)bh * 2048 * 64;
  const unsigned short* vb = vtw + (size_t)bh * 64 * 2048;
  const int dk0 = (wid * 64) * 8, dk1 = (wid * 64 + 256) * 8;
  const unsigned long long* mrow = mp + ((size_t)b * 2048 + qrow) * 32;

#define A_STAGE(T, BUF) { \
    const int jj = (T) * 64; \
    GLOAD_LDS(kb + (size_t)(jj + r0) * 64 + cc0 * 8, &lK[BUF][dk0]); \
    GLOAD_LDS(kb + (size_t)(jj + r1) * 64 + cc1 * 8, &lK[BUF][dk1]); \
    GLOAD_LDS(vb + (size_t)r0 * 2048 + jj + cc0 * 8, &lV[BUF][dk0]); \
    GLOAD_LDS(vb + (size_t)r1 * 2048 + jj + cc1 * 8, &lV[BUF][dk1]); }

  float m_i = -1e30f, l_i = 0.f;
  f32x4 o[4] = {};
  const int sw  = (l15 & 7) << 4;
  char* pb = (char*)lP[wid];

  A_STAGE(0, 0)
  __syncthreads();
  int cur = 0;

  for (int t = 0; t < 32; t++){
    if (t < 31) A_STAGE(t + 1, cur ^ 1)

    // S^T = K @ Q  (lane: j = jt*16 + l4*4 + r, i = l15)
    const char* kbase = (const char*)lK[cur];
    f32x4 st[4];
    __builtin_amdgcn_s_setprio(1);
    #pragma unroll
    for (int jt = 0; jt < 4; jt++){
      const int base = (jt * 16 + l15) * 128 + l4 * 16;
      const short8 a0 = *reinterpret_cast<const short8*>(kbase + ((base     ) ^ sw));
      const short8 a1 = *reinterpret_cast<const short8*>(kbase + ((base + 64) ^ sw));
      f32x4 z = {0.f, 0.f, 0.f, 0.f};
      z = __builtin_amdgcn_mfma_f32_16x16x32_bf16(a0, qf0, z, 0, 0, 0);
      z = __builtin_amdgcn_mfma_f32_16x16x32_bf16(a1, qf1, z, 0, 0, 0);
      st[jt] = z;
    }
    __builtin_amdgcn_s_setprio(0);

    // mask + row max (exp2 domain; Q pre-scaled by 0.125*log2e)
    const unsigned long long mks = mrow[t] >> (l4 * 4);
    float tmax = -3e38f;
    #pragma unroll
    for (int jt = 0; jt < 4; jt++){
      const unsigned m4 = (unsigned)(mks >> (jt * 16)) & 15u;
      #pragma unroll
      for (int r = 0; r < 4; r++){
        float s = ((m4 >> r) & 1u) ? (float)st[jt][r] : -3e38f;
        st[jt][r] = s;
        tmax = fmaxf(tmax, s);
      }
    }
    tmax = fmaxf(tmax, __shfl_xor(tmax, 16));
    tmax = fmaxf(tmax, __shfl_xor(tmax, 32));

    // defer-max (T13, THR=8 in log2 units)
    if (!__all(tmax <= m_i + 8.f)){
      const float mnew = fmaxf(m_i, tmax);
      const float fac = exp2f(m_i - mnew);
      #pragma unroll
      for (int r = 0; r < 4; r++){
        const float fr = __shfl(fac, l4 * 4 + r);
        #pragma unroll
        for (int dt = 0; dt < 4; dt++) o[dt][r] *= fr;
      }
      l_i *= fac;
      m_i = mnew;
    }

    float psum = 0.f;
    #pragma unroll
    for (int jt = 0; jt < 4; jt++){
      ushort4 pk;
      #pragma unroll
      for (int r = 0; r < 4; r++){
        const float p = exp2f(st[jt][r] - m_i);   // masked: exp2(-3e38-m) == 0
        psum += p;
        ((unsigned short*)&pk)[r] = f2b(p);
      }
      *reinterpret_cast<ushort4*>(pb + ((l15 * 128 + jt * 32 + l4 * 8) ^ sw)) = pk;
    }
    psum += __shfl_xor(psum, 16);
    psum += __shfl_xor(psum, 32);
    l_i += psum;

    // PV
    const char* vbase = (const char*)lV[cur];
    __builtin_amdgcn_s_setprio(1);
    #pragma unroll
    for (int ks = 0; ks < 2; ks++){
      const short8 pa = *reinterpret_cast<const short8*>(pb + ((l15 * 128 + ks * 64 + l4 * 16) ^ sw));
      #pragma unroll
      for (int dt = 0; dt < 4; dt++){
        const int base = (dt * 16 + l15) * 128 + ks * 64 + l4 * 16;
        const short8 bv = *reinterpret_cast<const short8*>(vbase + (base ^ sw));
        o[dt] = __builtin_amdgcn_mfma_f32_16x16x32_bf16(pa, bv, o[dt], 0, 0, 0);
      }
    }
    __builtin_amdgcn_s_setprio(0);

    __syncthreads();
    cur ^= 1;
  }
#undef A_STAGE

  #pragma unroll
  for (int r = 0; r < 4; r++){
    const float li = __shfl(l_i, l4 * 4 + r);
    const float inv = 1.0f / li;
    const int n = qbase + wid * 16 + l4 * 4 + r;
    #pragma unroll
    for (int dt = 0; dt < 4; dt++){
      const int e = h * 64 + dt * 16 + l15;
      ao[((size_t)b * 2048 + n) * 1024 + e] = f2b(o[dt][r] * inv);
    }
  }
}

extern "C" void kernel_launch(void* const* d_in, const int* in_sizes, int n_in,
                              void* d_out, int out_size, void* d_ws, size_t ws_size,
                              hipStream_t stream){
  const float* x   = (const float*)d_in[0];
  const float* ctx = (const float*)d_in[1];
  const int*   tgt = (const int*)d_in[2];
  const void*  src = d_in[3];
  const float* Wq  = (const float*)d_in[4];
  const float* Wk  = (const float*)d_in[5];
  const float* Wv  = (const float*)d_in[6];
  const float* Wo  = (const float*)d_in[7];
  const float* bo  = (const float*)d_in[8];
  float* out = (float*)d_out;

  char* w = (char*)d_ws;
  unsigned short* xb   = (unsigned short*)(w);
  unsigned short* cb   = (unsigned short*)(w + (8u << 20));
  unsigned short* wqb  = (unsigned short*)(w + (16u << 20));
  unsigned short* wkvb = (unsigned short*)(w + (18u << 20));
  unsigned short* wob  = (unsigned short*)(w + (22u << 20));
  unsigned short* qws  = (unsigned short*)(w + (24u << 20));
  unsigned short* kws  = (unsigned short*)(w + (32u << 20));
  unsigned short* vtw  = (unsigned short*)(w + (40u << 20));
  unsigned short* ao   = (unsigned short*)(w + (48u << 20));
  unsigned long long* mp = (unsigned long long*)(w + (56u << 20));
  int* flag = (int*)(w + (57u << 20));

  convall<<<12288, 256, 0, stream>>>(x, ctx, Wq, Wk, Wv, Wo, xb, cb, wqb, wkvb, wob);
  detect_mask_dtype<<<1, 64, 0, stream>>>((const int*)src, flag);
  maskpack<<<32768, 256, 0, stream>>>(tgt, src, flag, mp);

  gemm_bt<0><<<dim3(8, 32),  256, 0, stream>>>(xb, wqb,  qws, nullptr, nullptr, nullptr);
  gemm_bt<1><<<dim3(16, 32), 256, 0, stream>>>(cb, wkvb, kws, vtw,     nullptr, nullptr);
  attn<<<dim3(32, 32), 256, 0, stream>>>(qws, kws, vtw, mp, ao);
  gemm_bt<2><<<dim3(8, 32),  256, 0, stream>>>(ao, wob,  nullptr, nullptr, out, bo);
}